// Round 1
// baseline (43506.860 us; speedup 1.0000x reference)
//
#include <hip/hip_runtime.h>
#include <hip/hip_cooperative_groups.h>

namespace cgrp = cooperative_groups;

#define BATCH 64
#define SEQ   512
#define DIM   1024
#define HID   1024
#define OUTF  1024
#define NGATE 4096

// ---------------------------------------------------------------------------
// fp32 tiled GEMM, 64x64 tile, BK=16, 256 threads, 4x4 per thread.
// One M-tile == one timestep (BM == BATCH == 64).
// ---------------------------------------------------------------------------

// Xp[tc][b][g*1024+j] = sum_k x[b][t0+tc][k] * Wg[k][j] + bg[j]
__global__ __launch_bounds__(256, 4)
void xproj_kernel(const float* __restrict__ x,
                  const float* __restrict__ Wf, const float* __restrict__ Wi,
                  const float* __restrict__ Wc, const float* __restrict__ Wo,
                  const float* __restrict__ bf, const float* __restrict__ bi,
                  const float* __restrict__ bc, const float* __restrict__ bo,
                  float* __restrict__ Xp, int t0)
{
    __shared__ float As[16][68];   // As[kk][m] (transposed A tile)
    __shared__ float Bs[16][68];   // Bs[kk][n]
    const int tid = threadIdx.x;
    const int nt  = blockIdx.x & 63;     // 64 n-tiles over 4096 gate cols
    const int mt  = blockIdx.x >> 6;     // chunk-local timestep
    const int gate = nt >> 4;
    const int j0   = (nt & 15) * 64;
    const float* Wg = (gate==0)?Wf:(gate==1)?Wi:(gate==2)?Wc:Wo;
    const float* bg = (gate==0)?bf:(gate==1)?bi:(gate==2)?bc:bo;

    const int am = tid >> 2;             // A row to load (== batch b)
    const int af = (tid & 3) * 4;        // k offset within tile
    const float* arow = x + ((size_t)am * SEQ + (t0 + mt)) * DIM + af;
    const int bk = tid >> 4;             // B row to load
    const int bn = (tid & 15) * 4;       // B col
    const float* bp = Wg + (size_t)bk * HID + j0 + bn;

    const int m0 = (tid >> 4) * 4;
    const int n0 = (tid & 15) * 4;
    float acc[4][4] = {};

    for (int k0 = 0; k0 < DIM; k0 += 16) {
        float4 av = *(const float4*)(arow + k0);
        float4 bv = *(const float4*)(bp + (size_t)k0 * HID);
        __syncthreads();
        As[af+0][am] = av.x; As[af+1][am] = av.y;
        As[af+2][am] = av.z; As[af+3][am] = av.w;
        *(float4*)&Bs[bk][bn] = bv;
        __syncthreads();
        #pragma unroll
        for (int kk = 0; kk < 16; ++kk) {
            float4 a = *(const float4*)&As[kk][m0];
            float4 b = *(const float4*)&Bs[kk][n0];
            acc[0][0] += a.x*b.x; acc[0][1] += a.x*b.y; acc[0][2] += a.x*b.z; acc[0][3] += a.x*b.w;
            acc[1][0] += a.y*b.x; acc[1][1] += a.y*b.y; acc[1][2] += a.y*b.z; acc[1][3] += a.y*b.w;
            acc[2][0] += a.z*b.x; acc[2][1] += a.z*b.y; acc[2][2] += a.z*b.z; acc[2][3] += a.z*b.w;
            acc[3][0] += a.w*b.x; acc[3][1] += a.w*b.y; acc[3][2] += a.w*b.z; acc[3][3] += a.w*b.w;
        }
    }
    const float4 bias = *(const float4*)(bg + j0 + n0);
    #pragma unroll
    for (int i = 0; i < 4; ++i) {
        float4 o;
        o.x = acc[i][0] + bias.x; o.y = acc[i][1] + bias.y;
        o.z = acc[i][2] + bias.z; o.w = acc[i][3] + bias.w;
        *(float4*)(Xp + ((size_t)mt*BATCH + m0 + i)*NGATE + gate*HID + j0 + n0) = o;
    }
}

// out[b][t0+mt][f] = sum_j Hc[mt][b][j] * Wout[j][f] + bout[f]
__global__ __launch_bounds__(256, 4)
void outproj_kernel(const float* __restrict__ Hc,
                    const float* __restrict__ Wout, const float* __restrict__ bout,
                    float* __restrict__ out, int t0)
{
    __shared__ float As[16][68];
    __shared__ float Bs[16][68];
    const int tid = threadIdx.x;
    const int nt  = blockIdx.x & 15;     // 16 n-tiles over 1024 out cols
    const int mt  = blockIdx.x >> 4;     // chunk-local timestep
    const int am = tid >> 2;
    const int af = (tid & 3) * 4;
    const float* arow = Hc + ((size_t)mt*BATCH + am) * HID + af;
    const int bk = tid >> 4;
    const int bn = (tid & 15) * 4;
    const float* bp = Wout + (size_t)bk * OUTF + nt*64 + bn;
    const int m0 = (tid >> 4) * 4;
    const int n0 = (tid & 15) * 4;
    float acc[4][4] = {};

    for (int k0 = 0; k0 < HID; k0 += 16) {
        float4 av = *(const float4*)(arow + k0);
        float4 bv = *(const float4*)(bp + (size_t)k0 * OUTF);
        __syncthreads();
        As[af+0][am] = av.x; As[af+1][am] = av.y;
        As[af+2][am] = av.z; As[af+3][am] = av.w;
        *(float4*)&Bs[bk][bn] = bv;
        __syncthreads();
        #pragma unroll
        for (int kk = 0; kk < 16; ++kk) {
            float4 a = *(const float4*)&As[kk][m0];
            float4 b = *(const float4*)&Bs[kk][n0];
            acc[0][0] += a.x*b.x; acc[0][1] += a.x*b.y; acc[0][2] += a.x*b.z; acc[0][3] += a.x*b.w;
            acc[1][0] += a.y*b.x; acc[1][1] += a.y*b.y; acc[1][2] += a.y*b.z; acc[1][3] += a.y*b.w;
            acc[2][0] += a.z*b.x; acc[2][1] += a.z*b.y; acc[2][2] += a.z*b.z; acc[2][3] += a.z*b.w;
            acc[3][0] += a.w*b.x; acc[3][1] += a.w*b.y; acc[3][2] += a.w*b.z; acc[3][3] += a.w*b.w;
        }
    }
    const float4 bias = *(const float4*)(bout + nt*64 + n0);
    const int s = t0 + mt;
    #pragma unroll
    for (int i = 0; i < 4; ++i) {
        float4 o;
        o.x = acc[i][0] + bias.x; o.y = acc[i][1] + bias.y;
        o.z = acc[i][2] + bias.z; o.w = acc[i][3] + bias.w;
        *(float4*)(out + ((size_t)(m0+i)*SEQ + s)*OUTF + nt*64 + n0) = o;
    }
}

// ---------------------------------------------------------------------------
// Cooperative recurrence over one chunk of timesteps.
// 256 blocks x 512 threads, 1 block/CU.
// Block = (cgi, kq): 64 gate-cols [cgi*64, +64) x k-quarter [kq*256, +256).
// Phase 1: partial gate GEMM -> Gpart[kq][b][n].  grid.sync.
// Phase 2: reduce partials + Xp, activations, c/h update. grid.sync.
// W_h cols persistent in LDS; h staged per-step with XOR swizzle (b128-clean).
// ---------------------------------------------------------------------------
__global__ __launch_bounds__(512, 2)
void lstm_chunk(const float* __restrict__ Wf, const float* __restrict__ Wi,
                const float* __restrict__ Wc, const float* __restrict__ Wo,
                const float* __restrict__ Xp,
                const float* __restrict__ h0, const float* __restrict__ c0,
                float* __restrict__ Hall, float* __restrict__ hcarry,
                float* __restrict__ Cbuf, float* __restrict__ Gpart,
                int t0, int nsteps)
{
    __shared__ float Alds[BATCH][256];   // h tile (swizzled in 16B chunks): 64 KB
    __shared__ float Blds[64][260];      // W_h columns [c][kk], padded: 66.6 KB
    cgrp::grid_group grid = cgrp::this_grid();

    const int tid = threadIdx.x;
    const int bid = blockIdx.x;
    const int cgi = bid >> 2;
    const int kq  = bid & 3;
    const int n0  = cgi * 64;            // global gate-col base
    const int gate = n0 >> 10;
    const int j0  = n0 & 1023;
    const int k0  = kq * 256;
    const float* Wg = (gate==0)?Wf:(gate==1)?Wi:(gate==2)?Wc:Wo;

    // persistent B stage (once per chunk): Blds[c][kk] = Wg[D+k0+kk][j0+c]
    for (int idx = tid; idx < 64*256; idx += 512) {
        int kk = idx >> 6, c = idx & 63;
        Blds[c][kk] = Wg[(size_t)(DIM + k0 + kk) * HID + j0 + c];
    }
    __syncthreads();

    const int bq  = tid & 15;            // batch quad: rows bq*4..bq*4+3
    const int chp = tid >> 4;            // col pair: cols chp*2, chp*2+1
    const int swz = bq & 7;
    float4* A4 = (float4*)&Alds[0][0];

    for (int tc = 0; tc < nsteps; ++tc) {
        const int tg = t0 + tc;
        const float* hprev = (tc == 0) ? ((tg == 0) ? h0 : hcarry)
                                       : (Hall + (size_t)(tc-1)*BATCH*HID);
        // stage h[64][k0..k0+255] into LDS, 16B-chunk XOR swizzle by (b>>2)&7
        #pragma unroll
        for (int rep = 0; rep < 8; ++rep) {
            int idx = rep*512 + tid;
            int b  = idx >> 6;
            int c4 = idx & 63;
            float4 v = *(const float4*)(hprev + (size_t)b*HID + k0 + c4*4);
            A4[b*64 + (c4 ^ ((b>>2)&7))] = v;
        }
        __syncthreads();

        float acc00=0,acc01=0,acc10=0,acc11=0,acc20=0,acc21=0,acc30=0,acc31=0;
        #pragma unroll 2
        for (int k4 = 0; k4 < 64; ++k4) {
            const int ai = k4 ^ swz;
            float4 a0 = A4[(bq*4+0)*64 + ai];
            float4 a1 = A4[(bq*4+1)*64 + ai];
            float4 a2 = A4[(bq*4+2)*64 + ai];
            float4 a3 = A4[(bq*4+3)*64 + ai];
            float4 w0 = *(const float4*)&Blds[chp*2+0][k4*4];
            float4 w1 = *(const float4*)&Blds[chp*2+1][k4*4];
            acc00 += a0.x*w0.x + a0.y*w0.y + a0.z*w0.z + a0.w*w0.w;
            acc01 += a0.x*w1.x + a0.y*w1.y + a0.z*w1.z + a0.w*w1.w;
            acc10 += a1.x*w0.x + a1.y*w0.y + a1.z*w0.z + a1.w*w0.w;
            acc11 += a1.x*w1.x + a1.y*w1.y + a1.z*w1.z + a1.w*w1.w;
            acc20 += a2.x*w0.x + a2.y*w0.y + a2.z*w0.z + a2.w*w0.w;
            acc21 += a2.x*w1.x + a2.y*w1.y + a2.z*w1.z + a2.w*w1.w;
            acc30 += a3.x*w0.x + a3.y*w0.y + a3.z*w0.z + a3.w*w0.w;
            acc31 += a3.x*w1.x + a3.y*w1.y + a3.z*w1.z + a3.w*w1.w;
        }
        {
            float* gp = Gpart + (size_t)kq * BATCH * NGATE + n0 + chp*2;
            *(float2*)(gp + (size_t)(bq*4+0)*NGATE) = make_float2(acc00, acc01);
            *(float2*)(gp + (size_t)(bq*4+1)*NGATE) = make_float2(acc10, acc11);
            *(float2*)(gp + (size_t)(bq*4+2)*NGATE) = make_float2(acc20, acc21);
            *(float2*)(gp + (size_t)(bq*4+3)*NGATE) = make_float2(acc30, acc31);
        }
        grid.sync();

        // phase 2: elementwise (first 128 blocks cover all 64*1024 h-elems)
        int gid = bid*512 + tid;
        if (gid < BATCH*HID) {
            int b = gid >> 10, j = gid & 1023;
            const float* gb = Gpart + (size_t)b*NGATE + j;
            float g0=0, g1=0, g2=0, g3=0;
            #pragma unroll
            for (int q = 0; q < 4; ++q) {
                const float* gq = gb + (size_t)q*BATCH*NGATE;
                g0 += gq[0]; g1 += gq[HID]; g2 += gq[2*HID]; g3 += gq[3*HID];
            }
            const float* xp = Xp + (size_t)tc*BATCH*NGATE + (size_t)b*NGATE + j;
            g0 += xp[0]; g1 += xp[HID]; g2 += xp[2*HID]; g3 += xp[3*HID];
            float fg  = 1.f/(1.f + __expf(-g0));
            float ig  = 1.f/(1.f + __expf(-g1));
            float ct  = tanhf(g2);
            float og  = 1.f/(1.f + __expf(-g3));
            float cp  = (tg == 0) ? c0[gid] : Cbuf[gid];
            float cn  = fg*cp + ig*ct;
            float hn  = og * tanhf(cn);
            Cbuf[gid] = cn;
            Hall[(size_t)tc*BATCH*HID + gid] = hn;
            if (tc == nsteps-1) hcarry[gid] = hn;
        }
        grid.sync();
    }
}

// ---------------------------------------------------------------------------

extern "C" void kernel_launch(void* const* d_in, const int* in_sizes, int n_in,
                              void* d_out, int out_size, void* d_ws, size_t ws_size,
                              hipStream_t stream)
{
    const float* x    = (const float*)d_in[0];
    const float* h0   = (const float*)d_in[1];
    const float* c0   = (const float*)d_in[2];
    const float* Wf   = (const float*)d_in[3];
    const float* bf   = (const float*)d_in[4];
    const float* Wi   = (const float*)d_in[5];
    const float* bi   = (const float*)d_in[6];
    const float* Wc   = (const float*)d_in[7];
    const float* bc   = (const float*)d_in[8];
    const float* Wo   = (const float*)d_in[9];
    const float* bo   = (const float*)d_in[10];
    const float* Wout = (const float*)d_in[11];
    const float* bout = (const float*)d_in[12];
    float* out = (float*)d_out;

    // adaptive chunking: Xp chunk (1 MB/step) + Hc chunk (256 KB/step)
    //                    + Gpart 4 MB + Cbuf 256 KB + hcarry 256 KB
    const int cand[7] = {512, 256, 128, 64, 32, 16, 8};
    int chunk = 8;
    for (int i = 0; i < 7; ++i) {
        size_t need = (size_t)cand[i]*(1048576 + 262144) + 4u*1048576 + 2u*262144;
        if (need <= ws_size) { chunk = cand[i]; break; }
    }

    char* w = (char*)d_ws;
    float* Xp     = (float*)w;  w += (size_t)chunk*BATCH*NGATE*4;
    float* Hc     = (float*)w;  w += (size_t)chunk*BATCH*HID*4;
    float* Gpart  = (float*)w;  w += (size_t)4*BATCH*NGATE*4;
    float* Cbuf   = (float*)w;  w += (size_t)BATCH*HID*4;
    float* hcarry = (float*)w;

    for (int t0 = 0; t0 < SEQ; t0 += chunk) {
        xproj_kernel<<<dim3(chunk*64), dim3(256), 0, stream>>>(
            x, Wf, Wi, Wc, Wo, bf, bi, bc, bo, Xp, t0);

        int t0i = t0, ns = chunk;
        void* args[13] = { (void*)&Wf, (void*)&Wi, (void*)&Wc, (void*)&Wo,
                           (void*)&Xp, (void*)&h0, (void*)&c0,
                           (void*)&Hc, (void*)&hcarry, (void*)&Cbuf, (void*)&Gpart,
                           (void*)&t0i, (void*)&ns };
        hipLaunchCooperativeKernel((const void*)lstm_chunk, dim3(256), dim3(512),
                                   args, 0, stream);

        outproj_kernel<<<dim3(chunk*16), dim3(256), 0, stream>>>(
            Hc, Wout, bout, out, t0);
    }
}

// Round 2
// 24292.102 us; speedup vs baseline: 1.7910x; 1.7910x over previous
//
#include <hip/hip_runtime.h>
#include <hip/hip_cooperative_groups.h>

namespace cgrp = cooperative_groups;

#define BATCH 64
#define SEQ   512
#define DIM   1024
#define HID   1024
#define OUTF  1024
#define NGATE 4096

typedef float f32x4 __attribute__((ext_vector_type(4)));
typedef short bf16x8 __attribute__((ext_vector_type(8)));

static __device__ __forceinline__ unsigned short f2bf(float f) {
    unsigned int u = __float_as_uint(f);
    u = (u + 0x7FFFu + ((u >> 16) & 1u)) >> 16;   // round-to-nearest-even
    return (unsigned short)u;
}
static __device__ __forceinline__ float bf2f(unsigned short h) {
    return __uint_as_float(((unsigned int)h) << 16);
}

// ---------------------------------------------------------------------------
// One-time prep: pack recurrent W into per-block panels, split hi/lo bf16,
// pre-swizzled in 16B k-chunks (kc ^= n&7) so LDS reads are conflict-free.
// Layout: Wpk[bid][split][n][kc][8e], n = gate*4 + jj, 32768 elems per bid.
// ---------------------------------------------------------------------------
__global__ __launch_bounds__(256)
void prep_w(const float* __restrict__ Wf, const float* __restrict__ Wi,
            const float* __restrict__ Wc, const float* __restrict__ Wo,
            unsigned short* __restrict__ Wpk)
{
    int idx = blockIdx.x * 256 + threadIdx.x;   // 2^19 threads
    int j8 = idx & 127;                         // 8-column group
    int k  = (idx >> 7) & 1023;
    int g  = idx >> 17;                         // gate 0..3
    const float* W = (g==0)?Wf:(g==1)?Wi:(g==2)?Wc:Wo;
    const float* src = W + (size_t)(DIM + k) * HID + j8*8;
    int kc_log = k >> 3, e = k & 7;
    #pragma unroll
    for (int e2 = 0; e2 < 8; ++e2) {
        int j = j8*8 + e2;
        int bid = j >> 2, jj = j & 3;
        int n = g*4 + jj;
        int kcp = kc_log ^ (n & 7);
        float v = src[e2];
        unsigned short hi = f2bf(v);
        unsigned short lo = f2bf(v - bf2f(hi));
        size_t base = (size_t)bid*32768 + (size_t)n*1024 + (size_t)(kcp*8 + e);
        Wpk[base]         = hi;   // split 0
        Wpk[base + 16384] = lo;   // split 1
    }
}

__global__ __launch_bounds__(256)
void prep_h0(const float* __restrict__ h0,
             unsigned short* __restrict__ hsh, unsigned short* __restrict__ hsl)
{
    int idx = blockIdx.x * 256 + threadIdx.x;   // 65536
    float v = h0[idx];
    unsigned short hi = f2bf(v);
    hsh[idx] = hi;
    hsl[idx] = f2bf(v - bf2f(hi));
}

// ---------------------------------------------------------------------------
// fp32 tiled GEMM for projections (v1-verified, unchanged).
// ---------------------------------------------------------------------------
__global__ __launch_bounds__(256, 4)
void xproj_kernel(const float* __restrict__ x,
                  const float* __restrict__ Wf, const float* __restrict__ Wi,
                  const float* __restrict__ Wc, const float* __restrict__ Wo,
                  const float* __restrict__ bf, const float* __restrict__ bi,
                  const float* __restrict__ bc, const float* __restrict__ bo,
                  float* __restrict__ Xp, int t0)
{
    __shared__ float As[16][68];
    __shared__ float Bs[16][68];
    const int tid = threadIdx.x;
    const int nt  = blockIdx.x & 63;
    const int mt  = blockIdx.x >> 6;
    const int gate = nt >> 4;
    const int j0   = (nt & 15) * 64;
    const float* Wg = (gate==0)?Wf:(gate==1)?Wi:(gate==2)?Wc:Wo;
    const float* bg = (gate==0)?bf:(gate==1)?bi:(gate==2)?bc:bo;

    const int am = tid >> 2;
    const int af = (tid & 3) * 4;
    const float* arow = x + ((size_t)am * SEQ + (t0 + mt)) * DIM + af;
    const int bk = tid >> 4;
    const int bn = (tid & 15) * 4;
    const float* bp = Wg + (size_t)bk * HID + j0 + bn;

    const int m0 = (tid >> 4) * 4;
    const int n0 = (tid & 15) * 4;
    float acc[4][4] = {};

    for (int k0 = 0; k0 < DIM; k0 += 16) {
        float4 av = *(const float4*)(arow + k0);
        float4 bv = *(const float4*)(bp + (size_t)k0 * HID);
        __syncthreads();
        As[af+0][am] = av.x; As[af+1][am] = av.y;
        As[af+2][am] = av.z; As[af+3][am] = av.w;
        *(float4*)&Bs[bk][bn] = bv;
        __syncthreads();
        #pragma unroll
        for (int kk = 0; kk < 16; ++kk) {
            float4 a = *(const float4*)&As[kk][m0];
            float4 b = *(const float4*)&Bs[kk][n0];
            acc[0][0] += a.x*b.x; acc[0][1] += a.x*b.y; acc[0][2] += a.x*b.z; acc[0][3] += a.x*b.w;
            acc[1][0] += a.y*b.x; acc[1][1] += a.y*b.y; acc[1][2] += a.y*b.z; acc[1][3] += a.y*b.w;
            acc[2][0] += a.z*b.x; acc[2][1] += a.z*b.y; acc[2][2] += a.z*b.z; acc[2][3] += a.z*b.w;
            acc[3][0] += a.w*b.x; acc[3][1] += a.w*b.y; acc[3][2] += a.w*b.z; acc[3][3] += a.w*b.w;
        }
    }
    const float4 bias = *(const float4*)(bg + j0 + n0);
    #pragma unroll
    for (int i = 0; i < 4; ++i) {
        float4 o;
        o.x = acc[i][0] + bias.x; o.y = acc[i][1] + bias.y;
        o.z = acc[i][2] + bias.z; o.w = acc[i][3] + bias.w;
        *(float4*)(Xp + ((size_t)mt*BATCH + m0 + i)*NGATE + gate*HID + j0 + n0) = o;
    }
}

__global__ __launch_bounds__(256, 4)
void outproj_kernel(const float* __restrict__ Hc,
                    const float* __restrict__ Wout, const float* __restrict__ bout,
                    float* __restrict__ out, int t0)
{
    __shared__ float As[16][68];
    __shared__ float Bs[16][68];
    const int tid = threadIdx.x;
    const int nt  = blockIdx.x & 15;
    const int mt  = blockIdx.x >> 4;
    const int am = tid >> 2;
    const int af = (tid & 3) * 4;
    const float* arow = Hc + ((size_t)mt*BATCH + am) * HID + af;
    const int bk = tid >> 4;
    const int bn = (tid & 15) * 4;
    const float* bp = Wout + (size_t)bk * OUTF + nt*64 + bn;
    const int m0 = (tid >> 4) * 4;
    const int n0 = (tid & 15) * 4;
    float acc[4][4] = {};

    for (int k0 = 0; k0 < HID; k0 += 16) {
        float4 av = *(const float4*)(arow + k0);
        float4 bv = *(const float4*)(bp + (size_t)k0 * OUTF);
        __syncthreads();
        As[af+0][am] = av.x; As[af+1][am] = av.y;
        As[af+2][am] = av.z; As[af+3][am] = av.w;
        *(float4*)&Bs[bk][bn] = bv;
        __syncthreads();
        #pragma unroll
        for (int kk = 0; kk < 16; ++kk) {
            float4 a = *(const float4*)&As[kk][m0];
            float4 b = *(const float4*)&Bs[kk][n0];
            acc[0][0] += a.x*b.x; acc[0][1] += a.x*b.y; acc[0][2] += a.x*b.z; acc[0][3] += a.x*b.w;
            acc[1][0] += a.y*b.x; acc[1][1] += a.y*b.y; acc[1][2] += a.y*b.z; acc[1][3] += a.y*b.w;
            acc[2][0] += a.z*b.x; acc[2][1] += a.z*b.y; acc[2][2] += a.z*b.z; acc[2][3] += a.z*b.w;
            acc[3][0] += a.w*b.x; acc[3][1] += a.w*b.y; acc[3][2] += a.w*b.z; acc[3][3] += a.w*b.w;
        }
    }
    const float4 bias = *(const float4*)(bout + nt*64 + n0);
    const int s = t0 + mt;
    #pragma unroll
    for (int i = 0; i < 4; ++i) {
        float4 o;
        o.x = acc[i][0] + bias.x; o.y = acc[i][1] + bias.y;
        o.z = acc[i][2] + bias.z; o.w = acc[i][3] + bias.w;
        *(float4*)(out + ((size_t)(m0+i)*SEQ + s)*OUTF + nt*64 + n0) = o;
    }
}

// ---------------------------------------------------------------------------
// Cooperative MFMA recurrence. 256 blocks x 256 threads (4 waves), 1 blk/CU.
// Block bid owns h-cols j0..j0+3 -> 16 gate cols (n = gate*4 + jj), FULL K.
// W panel (bf16 hi/lo, pre-swizzled) persistent in LDS: 64 KB.
// h hi/lo staged per step, 4 K-chunks of 256, XOR-swizzled dest.
// 3-term split MFMA: Ahi*Whi + Alo*Whi + Ahi*Wlo (fp32-accurate).
// Gates -> activations -> c (register-resident) -> h written to global.
// ONE grid.sync per step. No partial-sum global traffic.
// ---------------------------------------------------------------------------
__global__ __launch_bounds__(256, 1)
void lstm_mfma(const unsigned short* __restrict__ Wpk,
               const float* __restrict__ Xp,
               const float* __restrict__ c0,
               unsigned short* __restrict__ hsh0, unsigned short* __restrict__ hsl0,
               unsigned short* __restrict__ hsh1, unsigned short* __restrict__ hsl1,
               float* __restrict__ Hall, float* __restrict__ Cbuf,
               int t0, int nsteps)
{
    __shared__ __align__(16) unsigned short Wlds[2][16][1024];  // 64 KB
    __shared__ __align__(16) unsigned short Hlds[2][64][256];   // 64 KB
    __shared__ float Gbuf[64][17];                              // 4.4 KB
    cgrp::grid_group grid = cgrp::this_grid();

    const int tid  = threadIdx.x;
    const int bid  = blockIdx.x;
    const int lane = tid & 63;
    const int w    = tid >> 6;          // wave id = M-tile (rows w*16..+15)
    const int j0   = bid * 4;

    // persistent W panel: linear 64 KB copy (pre-swizzled in global)
    {
        const uint4* src = (const uint4*)(Wpk + (size_t)bid * 32768);
        uint4* dst = (uint4*)&Wlds[0][0][0];
        for (int i = tid; i < 4096; i += 256) dst[i] = src[i];
    }

    // c state in registers: thread t handles (eb = t>>2, ejj = t&3)
    const int eb = tid >> 2, ejj = tid & 3;
    float creg = (t0 == 0) ? c0[(size_t)eb*HID + j0 + ejj]
                           : Cbuf[(size_t)eb*HID + j0 + ejj];
    __syncthreads();

    // fragment address constants (16x16x32 layout: row/col = lane&15,
    // k = 8*(lane>>4) + e; C/D: col = lane&15, row = 4*(lane>>4) + reg)
    const int fb  = (w << 4) + (lane & 15);   // A row (batch)
    const int fn  = lane & 15;                // B col (gate col n)
    const int fkq = lane >> 4;                // k quarter

    for (int tc = 0; tc < nsteps; ++tc) {
        const int tg = t0 + tc;
        const unsigned short* hh = (tg & 1) ? hsh1 : hsh0;
        const unsigned short* hl = (tg & 1) ? hsl1 : hsl0;

        f32x4 acc = {0.f, 0.f, 0.f, 0.f};

        for (int cc = 0; cc < 4; ++cc) {
            // stage h[64][cc*256..+256) hi+lo; swizzled LDS dest (q ^= b&7)
            {
                const int q  = lane & 31;
                const int br = lane >> 5;
                #pragma unroll
                for (int ii = 0; ii < 8; ++ii) {
                    int b  = (w << 4) + ii*2 + br;
                    int qp = q ^ (b & 7);
                    uint4 v0 = *(const uint4*)(hh + (size_t)b*HID + cc*256 + q*8);
                    uint4 v1 = *(const uint4*)(hl + (size_t)b*HID + cc*256 + q*8);
                    *(uint4*)&Hlds[0][b][qp*8] = v0;
                    *(uint4*)&Hlds[1][b][qp*8] = v1;
                }
            }
            __syncthreads();
            #pragma unroll
            for (int ksl = 0; ksl < 8; ++ksl) {
                int qpA = ((ksl << 2) + fkq) ^ (lane & 7);
                int kcp = (((cc*8 + ksl) << 2) + fkq) ^ (fn & 7);
                bf16x8 ahi = *(const bf16x8*)&Hlds[0][fb][qpA << 3];
                bf16x8 alo = *(const bf16x8*)&Hlds[1][fb][qpA << 3];
                bf16x8 whi = *(const bf16x8*)&Wlds[0][fn][kcp << 3];
                bf16x8 wlo = *(const bf16x8*)&Wlds[1][fn][kcp << 3];
                acc = __builtin_amdgcn_mfma_f32_16x16x32_bf16(ahi, whi, acc, 0, 0, 0);
                acc = __builtin_amdgcn_mfma_f32_16x16x32_bf16(alo, whi, acc, 0, 0, 0);
                acc = __builtin_amdgcn_mfma_f32_16x16x32_bf16(ahi, wlo, acc, 0, 0, 0);
            }
            __syncthreads();
        }

        // scatter gate pre-activations to LDS
        #pragma unroll
        for (int r = 0; r < 4; ++r)
            Gbuf[(w << 4) + ((lane >> 4) << 2) + r][lane & 15] = acc[r];
        __syncthreads();

        // elementwise LSTM cell for (eb, j0+ejj)
        {
            const float* xpb = Xp + ((size_t)tc*BATCH + eb) * NGATE;
            float gf = Gbuf[eb][ejj +  0] + xpb[0*HID + j0 + ejj];
            float gi = Gbuf[eb][ejj +  4] + xpb[1*HID + j0 + ejj];
            float gc = Gbuf[eb][ejj +  8] + xpb[2*HID + j0 + ejj];
            float go = Gbuf[eb][ejj + 12] + xpb[3*HID + j0 + ejj];
            float f_ = 1.f/(1.f + __expf(-gf));
            float i_ = 1.f/(1.f + __expf(-gi));
            float c_ = tanhf(gc);
            float o_ = 1.f/(1.f + __expf(-go));
            float cn = f_*creg + i_*c_;
            float hn = o_*tanhf(cn);
            creg = cn;
            Hall[((size_t)tc*BATCH + eb)*HID + j0 + ejj] = hn;
            unsigned short hi = f2bf(hn);
            unsigned short lo = f2bf(hn - bf2f(hi));
            unsigned short* nh = (tg & 1) ? hsh0 : hsh1;
            unsigned short* nl = (tg & 1) ? hsl0 : hsl1;
            nh[(size_t)eb*HID + j0 + ejj] = hi;
            nl[(size_t)eb*HID + j0 + ejj] = lo;
        }
        grid.sync();
    }
    Cbuf[(size_t)eb*HID + j0 + ejj] = creg;
}

// ---------------------------------------------------------------------------

extern "C" void kernel_launch(void* const* d_in, const int* in_sizes, int n_in,
                              void* d_out, int out_size, void* d_ws, size_t ws_size,
                              hipStream_t stream)
{
    (void)in_sizes; (void)n_in; (void)out_size;
    const float* x    = (const float*)d_in[0];
    const float* h0   = (const float*)d_in[1];
    const float* c0   = (const float*)d_in[2];
    const float* Wf   = (const float*)d_in[3];
    const float* bf   = (const float*)d_in[4];
    const float* Wi   = (const float*)d_in[5];
    const float* bi   = (const float*)d_in[6];
    const float* Wc   = (const float*)d_in[7];
    const float* bc   = (const float*)d_in[8];
    const float* Wo   = (const float*)d_in[9];
    const float* bo   = (const float*)d_in[10];
    const float* Wout = (const float*)d_in[11];
    const float* bout = (const float*)d_in[12];
    float* out = (float*)d_out;

    // ws: Wpk 16MB | hs (4 x 128KB) | Cbuf 256KB | Xp chunk*1MB | Hc chunk*256KB
    const size_t fixed = (size_t)16*1024*1024 + 4u*131072 + 262144;
    const int cand[7] = {512, 256, 128, 64, 32, 16, 8};
    int chunk = 8;
    for (int i = 0; i < 7; ++i) {
        size_t need = fixed + (size_t)cand[i]*(1048576 + 262144);
        if (need <= ws_size) { chunk = cand[i]; break; }
    }

    char* p = (char*)d_ws;
    unsigned short* Wpk  = (unsigned short*)p; p += (size_t)16*1024*1024;
    unsigned short* hsh0 = (unsigned short*)p; p += 131072;
    unsigned short* hsl0 = (unsigned short*)p; p += 131072;
    unsigned short* hsh1 = (unsigned short*)p; p += 131072;
    unsigned short* hsl1 = (unsigned short*)p; p += 131072;
    float* Cbuf = (float*)p; p += 262144;
    float* Xp   = (float*)p; p += (size_t)chunk*BATCH*NGATE*4;
    float* Hc   = (float*)p;

    prep_w<<<dim3(2048), dim3(256), 0, stream>>>(Wf, Wi, Wc, Wo, Wpk);
    prep_h0<<<dim3(256), dim3(256), 0, stream>>>(h0, hsh0, hsl0);

    for (int t0 = 0; t0 < SEQ; t0 += chunk) {
        xproj_kernel<<<dim3(chunk*64), dim3(256), 0, stream>>>(
            x, Wf, Wi, Wc, Wo, bf, bi, bc, bo, Xp, t0);

        int t0i = t0, ns = chunk;
        void* args[11] = { (void*)&Wpk, (void*)&Xp, (void*)&c0,
                           (void*)&hsh0, (void*)&hsl0, (void*)&hsh1, (void*)&hsl1,
                           (void*)&Hc, (void*)&Cbuf, (void*)&t0i, (void*)&ns };
        hipLaunchCooperativeKernel((const void*)lstm_mfma, dim3(256), dim3(256),
                                   args, 0, stream);

        outproj_kernel<<<dim3(chunk*16), dim3(256), 0, stream>>>(
            Hc, Wout, bout, out, t0);
    }
}

// Round 3
// 23197.975 us; speedup vs baseline: 1.8755x; 1.0472x over previous
//
#include <hip/hip_runtime.h>
#include <hip/hip_cooperative_groups.h>

namespace cgrp = cooperative_groups;

#define BATCH 64
#define SEQ   512
#define DIM   1024
#define HID   1024
#define OUTF  1024
#define NGATE 4096

typedef float f32x4 __attribute__((ext_vector_type(4)));
typedef short bf16x8 __attribute__((ext_vector_type(8)));

static __device__ __forceinline__ unsigned short f2bf(float f) {
    unsigned int u = __float_as_uint(f);
    u = (u + 0x7FFFu + ((u >> 16) & 1u)) >> 16;   // round-to-nearest-even
    return (unsigned short)u;
}
static __device__ __forceinline__ float bf2f(unsigned short h) {
    return __uint_as_float(((unsigned int)h) << 16);
}

// ---------------------------------------------------------------------------
// Pack recurrent W as direct-load MFMA fragments, hi/lo bf16 split.
// Block bid (of 128) owns h-cols [bid*8, +8) -> 32 gate cols n = g*8 + jj.
// Layout: Wpk[bid][ks(32)][nt(2)][split(2)][lane(64)][e(8)]  (16 MB total)
//   fragment (ks, nt): lane l holds W[n = nt*16+(l&15)][k = ks*32+(l>>4)*8+e]
// ---------------------------------------------------------------------------
__global__ __launch_bounds__(256)
void prep_w(const float* __restrict__ Wf, const float* __restrict__ Wi,
            const float* __restrict__ Wc, const float* __restrict__ Wo,
            unsigned short* __restrict__ Wpk)
{
    int idx  = blockIdx.x * 256 + threadIdx.x;   // 524288 threads
    int lane = idx & 63;
    int nt   = (idx >> 6) & 1;
    int ks   = (idx >> 7) & 31;
    int bid  = idx >> 12;
    int nl   = nt * 16 + (lane & 15);            // local gate col 0..31
    int g    = nl >> 3, jj = nl & 7;
    int col  = bid * 8 + jj;                     // global h-col
    int k0   = ks * 32 + (lane >> 4) * 8;
    const float* W = (g==0)?Wf:(g==1)?Wi:(g==2)?Wc:Wo;
    size_t dst = (size_t)bid*65536 + (size_t)ks*2048 + (size_t)nt*1024 + (size_t)lane*8;
    #pragma unroll
    for (int e = 0; e < 8; ++e) {
        float v = W[(size_t)(DIM + k0 + e) * HID + col];
        unsigned short hi = f2bf(v);
        Wpk[dst + e]       = hi;                  // split 0 (hi)
        Wpk[dst + 512 + e] = f2bf(v - bf2f(hi));  // split 1 (lo)
    }
}

__global__ __launch_bounds__(256)
void prep_h0(const float* __restrict__ h0,
             unsigned short* __restrict__ hsh, unsigned short* __restrict__ hsl)
{
    int idx = blockIdx.x * 256 + threadIdx.x;   // 65536
    float v = h0[idx];
    unsigned short hi = f2bf(v);
    hsh[idx] = hi;
    hsl[idx] = f2bf(v - bf2f(hi));
}

// ---------------------------------------------------------------------------
// fp32 tiled GEMM for projections (verified in rounds 1-2, unchanged).
// ---------------------------------------------------------------------------
__global__ __launch_bounds__(256, 4)
void xproj_kernel(const float* __restrict__ x,
                  const float* __restrict__ Wf, const float* __restrict__ Wi,
                  const float* __restrict__ Wc, const float* __restrict__ Wo,
                  const float* __restrict__ bf, const float* __restrict__ bi,
                  const float* __restrict__ bc, const float* __restrict__ bo,
                  float* __restrict__ Xp, int t0)
{
    __shared__ float As[16][68];
    __shared__ float Bs[16][68];
    const int tid = threadIdx.x;
    const int nt  = blockIdx.x & 63;
    const int mt  = blockIdx.x >> 6;
    const int gate = nt >> 4;
    const int j0   = (nt & 15) * 64;
    const float* Wg = (gate==0)?Wf:(gate==1)?Wi:(gate==2)?Wc:Wo;
    const float* bg = (gate==0)?bf:(gate==1)?bi:(gate==2)?bc:bo;

    const int am = tid >> 2;
    const int af = (tid & 3) * 4;
    const float* arow = x + ((size_t)am * SEQ + (t0 + mt)) * DIM + af;
    const int bk = tid >> 4;
    const int bn = (tid & 15) * 4;
    const float* bp = Wg + (size_t)bk * HID + j0 + bn;

    const int m0 = (tid >> 4) * 4;
    const int n0 = (tid & 15) * 4;
    float acc[4][4] = {};

    for (int k0 = 0; k0 < DIM; k0 += 16) {
        float4 av = *(const float4*)(arow + k0);
        float4 bv = *(const float4*)(bp + (size_t)k0 * HID);
        __syncthreads();
        As[af+0][am] = av.x; As[af+1][am] = av.y;
        As[af+2][am] = av.z; As[af+3][am] = av.w;
        *(float4*)&Bs[bk][bn] = bv;
        __syncthreads();
        #pragma unroll
        for (int kk = 0; kk < 16; ++kk) {
            float4 a = *(const float4*)&As[kk][m0];
            float4 b = *(const float4*)&Bs[kk][n0];
            acc[0][0] += a.x*b.x; acc[0][1] += a.x*b.y; acc[0][2] += a.x*b.z; acc[0][3] += a.x*b.w;
            acc[1][0] += a.y*b.x; acc[1][1] += a.y*b.y; acc[1][2] += a.y*b.z; acc[1][3] += a.y*b.w;
            acc[2][0] += a.z*b.x; acc[2][1] += a.z*b.y; acc[2][2] += a.z*b.z; acc[2][3] += a.z*b.w;
            acc[3][0] += a.w*b.x; acc[3][1] += a.w*b.y; acc[3][2] += a.w*b.z; acc[3][3] += a.w*b.w;
        }
    }
    const float4 bias = *(const float4*)(bg + j0 + n0);
    #pragma unroll
    for (int i = 0; i < 4; ++i) {
        float4 o;
        o.x = acc[i][0] + bias.x; o.y = acc[i][1] + bias.y;
        o.z = acc[i][2] + bias.z; o.w = acc[i][3] + bias.w;
        *(float4*)(Xp + ((size_t)mt*BATCH + m0 + i)*NGATE + gate*HID + j0 + n0) = o;
    }
}

__global__ __launch_bounds__(256, 4)
void outproj_kernel(const float* __restrict__ Hc,
                    const float* __restrict__ Wout, const float* __restrict__ bout,
                    float* __restrict__ out, int t0)
{
    __shared__ float As[16][68];
    __shared__ float Bs[16][68];
    const int tid = threadIdx.x;
    const int nt  = blockIdx.x & 15;
    const int mt  = blockIdx.x >> 4;
    const int am = tid >> 2;
    const int af = (tid & 3) * 4;
    const float* arow = Hc + ((size_t)mt*BATCH + am) * HID + af;
    const int bk = tid >> 4;
    const int bn = (tid & 15) * 4;
    const float* bp = Wout + (size_t)bk * OUTF + nt*64 + bn;
    const int m0 = (tid >> 4) * 4;
    const int n0 = (tid & 15) * 4;
    float acc[4][4] = {};

    for (int k0 = 0; k0 < HID; k0 += 16) {
        float4 av = *(const float4*)(arow + k0);
        float4 bv = *(const float4*)(bp + (size_t)k0 * OUTF);
        __syncthreads();
        As[af+0][am] = av.x; As[af+1][am] = av.y;
        As[af+2][am] = av.z; As[af+3][am] = av.w;
        *(float4*)&Bs[bk][bn] = bv;
        __syncthreads();
        #pragma unroll
        for (int kk = 0; kk < 16; ++kk) {
            float4 a = *(const float4*)&As[kk][m0];
            float4 b = *(const float4*)&Bs[kk][n0];
            acc[0][0] += a.x*b.x; acc[0][1] += a.x*b.y; acc[0][2] += a.x*b.z; acc[0][3] += a.x*b.w;
            acc[1][0] += a.y*b.x; acc[1][1] += a.y*b.y; acc[1][2] += a.y*b.z; acc[1][3] += a.y*b.w;
            acc[2][0] += a.z*b.x; acc[2][1] += a.z*b.y; acc[2][2] += a.z*b.z; acc[2][3] += a.z*b.w;
            acc[3][0] += a.w*b.x; acc[3][1] += a.w*b.y; acc[3][2] += a.w*b.z; acc[3][3] += a.w*b.w;
        }
    }
    const float4 bias = *(const float4*)(bout + nt*64 + n0);
    const int s = t0 + mt;
    #pragma unroll
    for (int i = 0; i < 4; ++i) {
        float4 o;
        o.x = acc[i][0] + bias.x; o.y = acc[i][1] + bias.y;
        o.z = acc[i][2] + bias.z; o.w = acc[i][3] + bias.w;
        *(float4*)(out + ((size_t)(m0+i)*SEQ + s)*OUTF + nt*64 + n0) = o;
    }
}

// ---------------------------------------------------------------------------
// Cooperative MFMA recurrence, ZERO-LDS GEMM.
// 128 blocks x 512 threads (8 waves). Block owns 8 h-cols (32 gate cols).
// Wave w = (mt = w&3, nt = w>>2): 16x16 C tile, full K=1024, no partials.
// A (h hi/lo) and W (packed frags) load DIRECTLY global->VGPR; all 128
// 16B loads per wave per step are independent -> deep vmcnt pipeline,
// no __syncthreads in the GEMM. Xp prefetched into regs before the loop.
// One grid.sync per step.
// ---------------------------------------------------------------------------
__global__ __launch_bounds__(512, 1)
void lstm_mfma(const unsigned short* __restrict__ Wpk,
               const float* __restrict__ Xp,
               const float* __restrict__ c0,
               unsigned short* __restrict__ hsh0, unsigned short* __restrict__ hsl0,
               unsigned short* __restrict__ hsh1, unsigned short* __restrict__ hsl1,
               float* __restrict__ Hall, float* __restrict__ Cbuf,
               int t0, int nsteps)
{
    __shared__ float Gbuf[64][36];               // 9 KB
    cgrp::grid_group grid = cgrp::this_grid();

    const int tid  = threadIdx.x;
    const int bid  = blockIdx.x;
    const int lane = tid & 63;
    const int w    = tid >> 6;
    const int mt   = w & 3;                      // M tile (batch rows mt*16..+15)
    const int nt   = w >> 2;                     // N tile (gate cols nt*16..+15)
    const int j0   = bid * 8;

    // cell-state thread mapping: (eb, ejj) over 64 x 8
    const int eb = tid >> 3, ejj = tid & 7;
    float creg = (t0 == 0) ? c0[(size_t)eb*HID + j0 + ejj]
                           : Cbuf[(size_t)eb*HID + j0 + ejj];

    // fragment offsets
    const int arow = mt*16 + (lane & 15);
    const int aoff = arow*HID + (lane >> 4)*8;               // into h (elements)
    const unsigned short* wbase =
        Wpk + (size_t)bid*65536 + (size_t)nt*1024 + (size_t)lane*8;

    for (int tc = 0; tc < nsteps; ++tc) {
        const int tg = t0 + tc;
        const unsigned short* hh = (tg & 1) ? hsh1 : hsh0;
        const unsigned short* hl = (tg & 1) ? hsl1 : hsl0;
        unsigned short* nh = (tg & 1) ? hsh0 : hsh1;
        unsigned short* nl = (tg & 1) ? hsl0 : hsl1;

        // prefetch Xp slice for this thread's cell (independent of h)
        const float* xpb = Xp + ((size_t)tc*BATCH + eb)*NGATE + j0 + ejj;
        float xf = xpb[0], xi = xpb[HID], xc = xpb[2*HID], xo = xpb[3*HID];

        f32x4 acc = {0.f, 0.f, 0.f, 0.f};
        const unsigned short* ah = hh + aoff;
        const unsigned short* al = hl + aoff;
        #pragma unroll 8
        for (int ks = 0; ks < 32; ++ks) {
            bf16x8 vah = *(const bf16x8*)(ah + ks*32);
            bf16x8 val = *(const bf16x8*)(al + ks*32);
            bf16x8 vwh = *(const bf16x8*)(wbase + (size_t)ks*2048);
            bf16x8 vwl = *(const bf16x8*)(wbase + (size_t)ks*2048 + 512);
            acc = __builtin_amdgcn_mfma_f32_16x16x32_bf16(vah, vwh, acc, 0, 0, 0);
            acc = __builtin_amdgcn_mfma_f32_16x16x32_bf16(val, vwh, acc, 0, 0, 0);
            acc = __builtin_amdgcn_mfma_f32_16x16x32_bf16(vah, vwl, acc, 0, 0, 0);
        }

        // exchange gate tiles within the block
        #pragma unroll
        for (int r = 0; r < 4; ++r)
            Gbuf[mt*16 + (lane>>4)*4 + r][nt*16 + (lane&15)] = acc[r];
        __syncthreads();

        // LSTM cell for (eb, j0+ejj)
        {
            float gf = Gbuf[eb][0*8 + ejj] + xf;
            float gi = Gbuf[eb][1*8 + ejj] + xi;
            float gc = Gbuf[eb][2*8 + ejj] + xc;
            float go = Gbuf[eb][3*8 + ejj] + xo;
            float f_ = 1.f/(1.f + __expf(-gf));
            float i_ = 1.f/(1.f + __expf(-gi));
            float c_ = tanhf(gc);
            float o_ = 1.f/(1.f + __expf(-go));
            float cn = f_*creg + i_*c_;
            float hn = o_*tanhf(cn);
            creg = cn;
            Hall[((size_t)tc*BATCH + eb)*HID + j0 + ejj] = hn;
            unsigned short hi16 = f2bf(hn);
            nh[(size_t)eb*HID + j0 + ejj] = hi16;
            nl[(size_t)eb*HID + j0 + ejj] = f2bf(hn - bf2f(hi16));
        }
        grid.sync();   // orders h writes before next step's reads (and Gbuf reuse)
    }
    Cbuf[(size_t)eb*HID + j0 + ejj] = creg;
}

// ---------------------------------------------------------------------------

extern "C" void kernel_launch(void* const* d_in, const int* in_sizes, int n_in,
                              void* d_out, int out_size, void* d_ws, size_t ws_size,
                              hipStream_t stream)
{
    (void)in_sizes; (void)n_in; (void)out_size;
    const float* x    = (const float*)d_in[0];
    const float* h0   = (const float*)d_in[1];
    const float* c0   = (const float*)d_in[2];
    const float* Wf   = (const float*)d_in[3];
    const float* bf   = (const float*)d_in[4];
    const float* Wi   = (const float*)d_in[5];
    const float* bi   = (const float*)d_in[6];
    const float* Wc   = (const float*)d_in[7];
    const float* bc   = (const float*)d_in[8];
    const float* Wo   = (const float*)d_in[9];
    const float* bo   = (const float*)d_in[10];
    const float* Wout = (const float*)d_in[11];
    const float* bout = (const float*)d_in[12];
    float* out = (float*)d_out;

    // ws: Wpk 16MB | hs (4 x 128KB) | Cbuf 256KB | Xp chunk*1MB | Hc chunk*256KB
    const size_t fixed = (size_t)16*1024*1024 + 4u*131072 + 262144;
    const int cand[7] = {512, 256, 128, 64, 32, 16, 8};
    int chunk = 8;
    for (int i = 0; i < 7; ++i) {
        size_t need = fixed + (size_t)cand[i]*(1048576 + 262144);
        if (need <= ws_size) { chunk = cand[i]; break; }
    }

    char* p = (char*)d_ws;
    unsigned short* Wpk  = (unsigned short*)p; p += (size_t)16*1024*1024;
    unsigned short* hsh0 = (unsigned short*)p; p += 131072;
    unsigned short* hsl0 = (unsigned short*)p; p += 131072;
    unsigned short* hsh1 = (unsigned short*)p; p += 131072;
    unsigned short* hsl1 = (unsigned short*)p; p += 131072;
    float* Cbuf = (float*)p; p += 262144;
    float* Xp   = (float*)p; p += (size_t)chunk*BATCH*NGATE*4;
    float* Hc   = (float*)p;

    prep_w<<<dim3(2048), dim3(256), 0, stream>>>(Wf, Wi, Wc, Wo, Wpk);
    prep_h0<<<dim3(256), dim3(256), 0, stream>>>(h0, hsh0, hsl0);

    for (int t0 = 0; t0 < SEQ; t0 += chunk) {
        xproj_kernel<<<dim3(chunk*64), dim3(256), 0, stream>>>(
            x, Wf, Wi, Wc, Wo, bf, bi, bc, bo, Xp, t0);

        int t0i = t0, ns = chunk;
        void* args[11] = { (void*)&Wpk, (void*)&Xp, (void*)&c0,
                           (void*)&hsh0, (void*)&hsl0, (void*)&hsh1, (void*)&hsl1,
                           (void*)&Hc, (void*)&Cbuf, (void*)&t0i, (void*)&ns };
        hipLaunchCooperativeKernel((const void*)lstm_mfma, dim3(128), dim3(512),
                                   args, 0, stream);

        outproj_kernel<<<dim3(chunk*16), dim3(256), 0, stream>>>(
            Hc, Wout, bout, out, t0);
    }
}

// Round 4
// 17227.312 us; speedup vs baseline: 2.5255x; 1.3466x over previous
//
#include <hip/hip_runtime.h>

#define BATCH 64
#define SEQ   512
#define DIM   1024
#define HID   1024
#define OUTF  1024
#define NGATE 4096
#define NBLK  128   // recurrence blocks; barrier counts to NBLK per step

typedef float f32x4 __attribute__((ext_vector_type(4)));
typedef short bf16x8 __attribute__((ext_vector_type(8)));

static __device__ __forceinline__ unsigned short f2bf(float f) {
    unsigned int u = __float_as_uint(f);
    u = (u + 0x7FFFu + ((u >> 16) & 1u)) >> 16;   // round-to-nearest-even
    return (unsigned short)u;
}
static __device__ __forceinline__ float bf2f(unsigned short h) {
    return __uint_as_float(((unsigned int)h) << 16);
}

#define MFMA16(a, b, c) __builtin_amdgcn_mfma_f32_16x16x32_bf16((a), (b), (c), 0, 0, 0)

// ---------------------------------------------------------------------------
// prep: x fp32 -> bf16 hi/lo (error-compensated split), flat copy.
// ---------------------------------------------------------------------------
__global__ __launch_bounds__(256)
void prep_cvt_x(const float* __restrict__ x,
                unsigned short* __restrict__ xh, unsigned short* __restrict__ xl)
{
    size_t i = ((size_t)blockIdx.x * 256 + threadIdx.x) * 4;
    float4 v = *(const float4*)(x + i);
    float vv[4] = {v.x, v.y, v.z, v.w};
    #pragma unroll
    for (int e = 0; e < 4; ++e) {
        unsigned short hi = f2bf(vv[e]);
        xh[i + e] = hi;
        xl[i + e] = f2bf(vv[e] - bf2f(hi));
    }
}

// ---------------------------------------------------------------------------
// prep: recurrent W -> per-block fragment panels (grouped by h-col), hi/lo.
// Block bid (of 128) owns h-cols [bid*8,+8) -> 32 gate cols nl = g*8+jj.
// Layout: Wpk[bid][ks(32)][nt(2)]{hi[lane*8+e] | lo[512 + lane*8+e]}
// fragment: lane l holds W[nl = nt*16+(l&15)][k = ks*32+(l>>4)*8+e]
// (verified in rounds 2-3)
// ---------------------------------------------------------------------------
__global__ __launch_bounds__(256)
void prep_w(const float* __restrict__ Wf, const float* __restrict__ Wi,
            const float* __restrict__ Wc, const float* __restrict__ Wo,
            unsigned short* __restrict__ Wpk)
{
    int idx  = blockIdx.x * 256 + threadIdx.x;   // 524288 threads
    int lane = idx & 63;
    int nt   = (idx >> 6) & 1;
    int ks   = (idx >> 7) & 31;
    int bid  = idx >> 12;
    int nl   = nt * 16 + (lane & 15);
    int g    = nl >> 3, jj = nl & 7;
    int col  = bid * 8 + jj;
    int k0   = ks * 32 + (lane >> 4) * 8;
    const float* W = (g==0)?Wf:(g==1)?Wi:(g==2)?Wc:Wo;
    size_t dst = (size_t)bid*65536 + (size_t)ks*2048 + (size_t)nt*1024 + (size_t)lane*8;
    #pragma unroll
    for (int e = 0; e < 8; ++e) {
        float v = W[(size_t)(DIM + k0 + e) * HID + col];
        unsigned short hi = f2bf(v);
        Wpk[dst + e]       = hi;
        Wpk[dst + 512 + e] = f2bf(v - bf2f(hi));
    }
}

// ---------------------------------------------------------------------------
// prep: x-part of W_g -> consecutive-n fragment panels (for xproj).
// Panel nb (of 128) = gate cols [nb*32,+32); n = nb*32 + nt*16 + (l&15).
// ---------------------------------------------------------------------------
__global__ __launch_bounds__(256)
void prep_wg(const float* __restrict__ Wf, const float* __restrict__ Wi,
             const float* __restrict__ Wc, const float* __restrict__ Wo,
             unsigned short* __restrict__ Wgpk)
{
    int idx  = blockIdx.x * 256 + threadIdx.x;   // 524288 threads
    int lane = idx & 63;
    int nt   = (idx >> 6) & 1;
    int ks   = (idx >> 7) & 31;
    int nb   = idx >> 12;
    int n    = nb * 32 + nt * 16 + (lane & 15);
    int g    = n >> 10, j = n & 1023;
    int k0   = ks * 32 + (lane >> 4) * 8;
    const float* W = (g==0)?Wf:(g==1)?Wi:(g==2)?Wc:Wo;
    size_t dst = (size_t)nb*65536 + (size_t)ks*2048 + (size_t)nt*1024 + (size_t)lane*8;
    #pragma unroll
    for (int e = 0; e < 8; ++e) {
        float v = W[(size_t)(k0 + e) * HID + j];   // rows 0..D-1 (x part)
        unsigned short hi = f2bf(v);
        Wgpk[dst + e]       = hi;
        Wgpk[dst + 512 + e] = f2bf(v - bf2f(hi));
    }
}

// ---------------------------------------------------------------------------
// prep: W_out -> consecutive-n fragment panels (32 panels of 32 cols).
// ---------------------------------------------------------------------------
__global__ __launch_bounds__(256)
void prep_wout(const float* __restrict__ Wout, unsigned short* __restrict__ Wopk)
{
    int idx  = blockIdx.x * 256 + threadIdx.x;   // 131072 threads
    int lane = idx & 63;
    int nt   = (idx >> 6) & 1;
    int ks   = (idx >> 7) & 31;
    int nb   = idx >> 12;                        // 0..31
    int f    = nb * 32 + nt * 16 + (lane & 15);
    int k0   = ks * 32 + (lane >> 4) * 8;
    size_t dst = (size_t)nb*65536 + (size_t)ks*2048 + (size_t)nt*1024 + (size_t)lane*8;
    #pragma unroll
    for (int e = 0; e < 8; ++e) {
        float v = Wout[(size_t)(k0 + e) * OUTF + f];
        unsigned short hi = f2bf(v);
        Wopk[dst + e]       = hi;
        Wopk[dst + 512 + e] = f2bf(v - bf2f(hi));
    }
}

// ---------------------------------------------------------------------------
// prep: h0 -> Hh/Hl slot 0; zero the barrier counter.
// ---------------------------------------------------------------------------
__global__ __launch_bounds__(256)
void prep_h0(const float* __restrict__ h0,
             unsigned short* __restrict__ Hh, unsigned short* __restrict__ Hl,
             unsigned int* ctr)
{
    int idx = blockIdx.x * 256 + threadIdx.x;   // 65536
    float v = h0[idx];
    unsigned short hi = f2bf(v);
    Hh[idx] = hi;
    Hl[idx] = f2bf(v - bf2f(hi));
    if (idx == 0)
        __hip_atomic_store(ctr, 0u, __ATOMIC_RELAXED, __HIP_MEMORY_SCOPE_AGENT);
}

// ---------------------------------------------------------------------------
// xproj: Xp[tc][b][n] = sum_k x_bf16[b][t][k] * Wg_bf16[k][n] + b_g[n]
// 3-term split MFMA. Grid = chunk*128 blocks x 512 thr (8 waves = 4mt x 2nt).
// ---------------------------------------------------------------------------
__global__ __launch_bounds__(512, 4)
void xproj_mfma(const unsigned short* __restrict__ xh,
                const unsigned short* __restrict__ xl,
                const unsigned short* __restrict__ Wgpk,
                const float* __restrict__ bf_, const float* __restrict__ bi_,
                const float* __restrict__ bc_, const float* __restrict__ bo_,
                float* __restrict__ Xp, int t0)
{
    const int tid = threadIdx.x, lane = tid & 63, w = tid >> 6;
    const int mt = w & 3, nt = w >> 2;
    const int nb = blockIdx.x & 127, tc = blockIdx.x >> 7;
    const int t  = t0 + tc;
    const int n  = nb*32 + nt*16 + (lane & 15);
    const int g  = n >> 10, j = n & 1023;
    const float* bg = (g==0)?bf_:(g==1)?bi_:(g==2)?bc_:bo_;
    const float bias = bg[j];
    const int brow = mt*16 + (lane & 15);
    const size_t abase = ((size_t)brow*SEQ + t)*DIM + (lane >> 4)*8;
    const unsigned short* wb = Wgpk + (size_t)nb*65536 + (size_t)nt*1024 + (size_t)lane*8;

    f32x4 acc = {0.f, 0.f, 0.f, 0.f};
    #pragma unroll 4
    for (int ks = 0; ks < 32; ++ks) {
        bf16x8 axh = *(const bf16x8*)(xh + abase + ks*32);
        bf16x8 axl = *(const bf16x8*)(xl + abase + ks*32);
        bf16x8 wh  = *(const bf16x8*)(wb + (size_t)ks*2048);
        bf16x8 wl  = *(const bf16x8*)(wb + (size_t)ks*2048 + 512);
        acc = MFMA16(axh, wh, acc);
        acc = MFMA16(axl, wh, acc);
        acc = MFMA16(axh, wl, acc);
    }
    #pragma unroll
    for (int r = 0; r < 4; ++r)
        Xp[((size_t)tc*BATCH + mt*16 + (lane>>4)*4 + r)*NGATE + n] = acc[r] + bias;
}

// ---------------------------------------------------------------------------
// outproj: out[b][t][f] = sum_k Hbf16[slot tc+1][b][k] * Wout[k][f] + bout[f]
// Grid = chunk*32 blocks x 512 thr.
// ---------------------------------------------------------------------------
__global__ __launch_bounds__(512, 4)
void outproj_mfma(const unsigned short* __restrict__ Hh,
                  const unsigned short* __restrict__ Hl,
                  const unsigned short* __restrict__ Wopk,
                  const float* __restrict__ bout,
                  float* __restrict__ out, int t0)
{
    const int tid = threadIdx.x, lane = tid & 63, w = tid >> 6;
    const int mt = w & 3, nt = w >> 2;
    const int nb = blockIdx.x & 31, tc = blockIdx.x >> 5;
    const int t  = t0 + tc;
    const int n  = nb*32 + nt*16 + (lane & 15);
    const float bias = bout[n];
    const int brow = mt*16 + (lane & 15);
    const size_t abase = ((size_t)(tc+1)*BATCH + brow)*HID + (lane >> 4)*8;
    const unsigned short* wb = Wopk + (size_t)nb*65536 + (size_t)nt*1024 + (size_t)lane*8;

    f32x4 acc = {0.f, 0.f, 0.f, 0.f};
    #pragma unroll 4
    for (int ks = 0; ks < 32; ++ks) {
        bf16x8 axh = *(const bf16x8*)(Hh + abase + ks*32);
        bf16x8 axl = *(const bf16x8*)(Hl + abase + ks*32);
        bf16x8 wh  = *(const bf16x8*)(wb + (size_t)ks*2048);
        bf16x8 wl  = *(const bf16x8*)(wb + (size_t)ks*2048 + 512);
        acc = MFMA16(axh, wh, acc);
        acc = MFMA16(axl, wh, acc);
        acc = MFMA16(axh, wl, acc);
    }
    #pragma unroll
    for (int r = 0; r < 4; ++r)
        out[((size_t)(mt*16 + (lane>>4)*4 + r)*SEQ + t)*OUTF + n] = acc[r] + bias;
}

// ---------------------------------------------------------------------------
// Recurrence. 128 blocks x 512 thr (co-resident via cooperative launch).
// h history = 257-slot ring of VIRGIN addresses per step -> plain cached
// READS are safe (no stale lines anywhere); WRITES are agent-scope (sc1,
// write-through to IC) so other XCDs see them. Hand-rolled barrier:
// vmcnt(0) + __syncthreads -> one agent atomicAdd per block -> tid0 spins
// on agent load. NO L2 writeback-invalidate anywhere -> W panels stay
// L2-resident for all 256 steps (the round-3 killer).
// Quarter-K register groups force ~32 loads in flight per wave.
// ---------------------------------------------------------------------------
__global__ __launch_bounds__(512, 2)
void lstm_mfma(const unsigned short* __restrict__ Wpk,
               const float* __restrict__ Xp,
               const float* __restrict__ c0,
               unsigned short* Hh, unsigned short* Hl,
               float* __restrict__ Cbuf,
               unsigned int* barrier_ctr,
               int t0, int nsteps)
{
    __shared__ float Gbuf[64][36];
    const int tid  = threadIdx.x;
    const int bid  = blockIdx.x;
    const int lane = tid & 63;
    const int w    = tid >> 6;
    const int mt   = w & 3;                      // M tile (batch rows mt*16..+15)
    const int nt   = w >> 2;                     // N tile (gate cols nt*16..+15)
    const int j0   = bid * 8;

    const int eb = tid >> 3, ejj = tid & 7;      // cell-state mapping 64x8
    float creg = (t0 == 0) ? c0[(size_t)eb*HID + j0 + ejj]
                           : Cbuf[(size_t)eb*HID + j0 + ejj];

    const int arow = mt*16 + (lane & 15);
    const size_t abase = (size_t)arow*HID + (lane >> 4)*8;
    const unsigned short* wbase =
        Wpk + (size_t)bid*65536 + (size_t)nt*1024 + (size_t)lane*8;

    for (int tc = 0; tc < nsteps; ++tc) {
        // Xp prefetch (independent of h; nt to avoid polluting L2's W set)
        const float* xpb = Xp + ((size_t)tc*BATCH + eb)*NGATE + j0 + ejj;
        float xf = __builtin_nontemporal_load(xpb);
        float xi = __builtin_nontemporal_load(xpb + HID);
        float xc = __builtin_nontemporal_load(xpb + 2*HID);
        float xo = __builtin_nontemporal_load(xpb + 3*HID);

        const unsigned short* ah = Hh + (size_t)tc*(BATCH*HID) + abase;
        const unsigned short* al = Hl + (size_t)tc*(BATCH*HID) + abase;

        f32x4 acc = {0.f, 0.f, 0.f, 0.f};
        for (int q = 0; q < 4; ++q) {
            bf16x8 af[16], wf[16];
            #pragma unroll
            for (int i = 0; i < 8; ++i) {
                const int ks = q*8 + i;
                af[2*i]   = *(const bf16x8*)(ah + ks*32);
                af[2*i+1] = *(const bf16x8*)(al + ks*32);
                wf[2*i]   = *(const bf16x8*)(wbase + (size_t)ks*2048);
                wf[2*i+1] = *(const bf16x8*)(wbase + (size_t)ks*2048 + 512);
            }
            #pragma unroll
            for (int i = 0; i < 8; ++i) {
                acc = MFMA16(af[2*i],   wf[2*i],   acc);
                acc = MFMA16(af[2*i+1], wf[2*i],   acc);
                acc = MFMA16(af[2*i],   wf[2*i+1], acc);
            }
        }

        // exchange gate tiles within the block
        #pragma unroll
        for (int r = 0; r < 4; ++r)
            Gbuf[mt*16 + (lane>>4)*4 + r][nt*16 + (lane&15)] = acc[r];
        __syncthreads();

        // LSTM cell for (eb, j0+ejj); h -> slot tc+1 via agent (sc1) stores
        {
            float gf = Gbuf[eb][ 0 + ejj] + xf;
            float gi = Gbuf[eb][ 8 + ejj] + xi;
            float gc = Gbuf[eb][16 + ejj] + xc;
            float go = Gbuf[eb][24 + ejj] + xo;
            float f_ = 1.f/(1.f + __expf(-gf));
            float i_ = 1.f/(1.f + __expf(-gi));
            float c_ = tanhf(gc);
            float o_ = 1.f/(1.f + __expf(-go));
            float cn = f_*creg + i_*c_;
            float hn = o_*tanhf(cn);
            creg = cn;
            unsigned short hi16 = f2bf(hn);
            unsigned short lo16 = f2bf(hn - bf2f(hi16));
            size_t ho = (size_t)(tc+1)*(BATCH*HID) + (size_t)eb*HID + j0 + ejj;
            __hip_atomic_store(Hh + ho, hi16, __ATOMIC_RELAXED, __HIP_MEMORY_SCOPE_AGENT);
            __hip_atomic_store(Hl + ho, lo16, __ATOMIC_RELAXED, __HIP_MEMORY_SCOPE_AGENT);
            if (tc == nsteps - 1) {        // refresh slot 0 for the next chunk
                size_t h0o = (size_t)eb*HID + j0 + ejj;
                __hip_atomic_store(Hh + h0o, hi16, __ATOMIC_RELAXED, __HIP_MEMORY_SCOPE_AGENT);
                __hip_atomic_store(Hl + h0o, lo16, __ATOMIC_RELAXED, __HIP_MEMORY_SCOPE_AGENT);
            }
        }

        // ---- hand-rolled grid barrier (no cache maintenance) ----
        asm volatile("s_waitcnt vmcnt(0)" ::: "memory");   // h stores at IC
        __syncthreads();                                    // whole block done
        if (tid == 0) {
            __hip_atomic_fetch_add(barrier_ctr, 1u, __ATOMIC_RELAXED,
                                   __HIP_MEMORY_SCOPE_AGENT);
            const unsigned int tgt = (unsigned int)(t0 + tc + 1) * NBLK;
            while (__hip_atomic_load(barrier_ctr, __ATOMIC_RELAXED,
                                     __HIP_MEMORY_SCOPE_AGENT) < tgt) { }
        }
        __syncthreads();
        asm volatile("" ::: "memory");
    }
    Cbuf[(size_t)eb*HID + j0 + ejj] = creg;
}

// ---------------------------------------------------------------------------

extern "C" void kernel_launch(void* const* d_in, const int* in_sizes, int n_in,
                              void* d_out, int out_size, void* d_ws, size_t ws_size,
                              hipStream_t stream)
{
    (void)in_sizes; (void)n_in; (void)out_size;
    const float* x    = (const float*)d_in[0];
    const float* h0   = (const float*)d_in[1];
    const float* c0   = (const float*)d_in[2];
    const float* Wf   = (const float*)d_in[3];
    const float* bf   = (const float*)d_in[4];
    const float* Wi   = (const float*)d_in[5];
    const float* bi   = (const float*)d_in[6];
    const float* Wc   = (const float*)d_in[7];
    const float* bc   = (const float*)d_in[8];
    const float* Wo   = (const float*)d_in[9];
    const float* bo   = (const float*)d_in[10];
    const float* Wout = (const float*)d_in[11];
    const float* bout = (const float*)d_in[12];
    float* out = (float*)d_out;

    // workspace layout
    const size_t SZ_WPK  = (size_t)16*1024*1024;   // recurrent W frags
    const size_t SZ_WGPK = (size_t)16*1024*1024;   // x-part W frags
    const size_t SZ_WOPK = (size_t)4*1024*1024;    // Wout frags
    const size_t SZ_XBF  = (size_t)BATCH*SEQ*DIM*2;// 64 MB each (xh, xl)
    const size_t SZ_CB   = (size_t)BATCH*HID*4;    // 256 KB
    const size_t fixed   = SZ_WPK + SZ_WGPK + SZ_WOPK + 2*SZ_XBF + SZ_CB + 256;

    const int cand[6] = {256, 128, 64, 32, 16, 8};
    int chunk = 8;
    for (int i = 0; i < 6; ++i) {
        size_t need = fixed + (size_t)(cand[i]+1)*BATCH*HID*2*2   // Hh+Hl ring
                            + (size_t)cand[i]*BATCH*NGATE*4;      // Xp
        if (need <= ws_size) { chunk = cand[i]; break; }
    }

    char* p = (char*)d_ws;
    unsigned short* Wpk  = (unsigned short*)p; p += SZ_WPK;
    unsigned short* Wgpk = (unsigned short*)p; p += SZ_WGPK;
    unsigned short* Wopk = (unsigned short*)p; p += SZ_WOPK;
    unsigned short* xh   = (unsigned short*)p; p += SZ_XBF;
    unsigned short* xl   = (unsigned short*)p; p += SZ_XBF;
    float*          Cbuf = (float*)p;          p += SZ_CB;
    unsigned int*   ctr  = (unsigned int*)p;   p += 256;
    unsigned short* Hh   = (unsigned short*)p; p += (size_t)(chunk+1)*BATCH*HID*2;
    unsigned short* Hl   = (unsigned short*)p; p += (size_t)(chunk+1)*BATCH*HID*2;
    float*          Xp   = (float*)p;

    prep_cvt_x<<<dim3(32768), dim3(256), 0, stream>>>(x, xh, xl);
    prep_w    <<<dim3(2048),  dim3(256), 0, stream>>>(Wf, Wi, Wc, Wo, Wpk);
    prep_wg   <<<dim3(2048),  dim3(256), 0, stream>>>(Wf, Wi, Wc, Wo, Wgpk);
    prep_wout <<<dim3(512),   dim3(256), 0, stream>>>(Wout, Wopk);
    prep_h0   <<<dim3(256),   dim3(256), 0, stream>>>(h0, Hh, Hl, ctr);

    for (int t0 = 0; t0 < SEQ; t0 += chunk) {
        xproj_mfma<<<dim3(chunk*128), dim3(512), 0, stream>>>(
            xh, xl, Wgpk, bf, bi, bc, bo, Xp, t0);

        int t0i = t0, ns = chunk;
        void* args[9] = { (void*)&Wpk, (void*)&Xp, (void*)&c0,
                          (void*)&Hh, (void*)&Hl, (void*)&Cbuf, (void*)&ctr,
                          (void*)&t0i, (void*)&ns };
        hipLaunchCooperativeKernel((const void*)lstm_mfma, dim3(NBLK), dim3(512),
                                   args, 0, stream);

        outproj_mfma<<<dim3(chunk*32), dim3(512), 0, stream>>>(
            Hh, Hl, Wopk, bout, out, t0);
    }
}

// Round 5
// 9996.602 us; speedup vs baseline: 4.3522x; 1.7233x over previous
//
#include <hip/hip_runtime.h>

#define BATCH 64
#define SEQ   512
#define DIM   1024
#define HID   1024
#define OUTF  1024
#define NGATE 4096
#define NBLK  256   // recurrence blocks (1 per CU); 16 groups of 16 for barrier

typedef float f32x4 __attribute__((ext_vector_type(4)));
typedef short bf16x8 __attribute__((ext_vector_type(8)));

static __device__ __forceinline__ unsigned short f2bf(float f) {
    unsigned int u = __float_as_uint(f);
    u = (u + 0x7FFFu + ((u >> 16) & 1u)) >> 16;   // round-to-nearest-even
    return (unsigned short)u;
}
static __device__ __forceinline__ float bf2f(unsigned short h) {
    return __uint_as_float(((unsigned int)h) << 16);
}

#define MFMA16(a, b, c) __builtin_amdgcn_mfma_f32_16x16x32_bf16((a), (b), (c), 0, 0, 0)

// Fragment-layout index for h element (b, j) within one 65536-elem slot:
// [bgrp(4)][ks(32)][lane(64)][e(8)];  lane = (b&15) | (((j>>3)&3)<<4), e = j&7.
static __device__ __forceinline__ size_t hfrag_off(int b, int j) {
    int bgrp = b >> 4, ks = j >> 5;
    int lane = (b & 15) | (((j >> 3) & 3) << 4);
    return ((size_t)(bgrp * 32 + ks) * 64 + lane) * 8 + (j & 7);
}

// ---------------------------------------------------------------------------
// prep: x fp32 -> bf16 hi/lo (error-compensated split), flat copy.
// ---------------------------------------------------------------------------
__global__ __launch_bounds__(256)
void prep_cvt_x(const float* __restrict__ x,
                unsigned short* __restrict__ xh, unsigned short* __restrict__ xl)
{
    size_t i = ((size_t)blockIdx.x * 256 + threadIdx.x) * 4;
    float4 v = *(const float4*)(x + i);
    float vv[4] = {v.x, v.y, v.z, v.w};
    #pragma unroll
    for (int e = 0; e < 4; ++e) {
        unsigned short hi = f2bf(vv[e]);
        xh[i + e] = hi;
        xl[i + e] = f2bf(vv[e] - bf2f(hi));
    }
}

// ---------------------------------------------------------------------------
// prep: recurrent W -> per-slab fragment panels (8 h-cols each), hi/lo.
// Panel cslab (of 128): gate cols nl = g*8+jj for h-cols cslab*8+jj.
// Layout: Wpk[cslab][ks(32)][nt(2)]{hi[lane*8+e] | lo[512+lane*8+e]}
// (verified rounds 2-4)
// ---------------------------------------------------------------------------
__global__ __launch_bounds__(256)
void prep_w(const float* __restrict__ Wf, const float* __restrict__ Wi,
            const float* __restrict__ Wc, const float* __restrict__ Wo,
            unsigned short* __restrict__ Wpk)
{
    int idx  = blockIdx.x * 256 + threadIdx.x;   // 524288 threads
    int lane = idx & 63;
    int nt   = (idx >> 6) & 1;
    int ks   = (idx >> 7) & 31;
    int bid  = idx >> 12;
    int nl   = nt * 16 + (lane & 15);
    int g    = nl >> 3, jj = nl & 7;
    int col  = bid * 8 + jj;
    int k0   = ks * 32 + (lane >> 4) * 8;
    const float* W = (g==0)?Wf:(g==1)?Wi:(g==2)?Wc:Wo;
    size_t dst = (size_t)bid*65536 + (size_t)ks*2048 + (size_t)nt*1024 + (size_t)lane*8;
    #pragma unroll
    for (int e = 0; e < 8; ++e) {
        float v = W[(size_t)(DIM + k0 + e) * HID + col];
        unsigned short hi = f2bf(v);
        Wpk[dst + e]       = hi;
        Wpk[dst + 512 + e] = f2bf(v - bf2f(hi));
    }
}

// ---------------------------------------------------------------------------
// prep: x-part of W_g -> consecutive-n fragment panels (for xproj).
// ---------------------------------------------------------------------------
__global__ __launch_bounds__(256)
void prep_wg(const float* __restrict__ Wf, const float* __restrict__ Wi,
             const float* __restrict__ Wc, const float* __restrict__ Wo,
             unsigned short* __restrict__ Wgpk)
{
    int idx  = blockIdx.x * 256 + threadIdx.x;   // 524288 threads
    int lane = idx & 63;
    int nt   = (idx >> 6) & 1;
    int ks   = (idx >> 7) & 31;
    int nb   = idx >> 12;
    int n    = nb * 32 + nt * 16 + (lane & 15);
    int g    = n >> 10, j = n & 1023;
    int k0   = ks * 32 + (lane >> 4) * 8;
    const float* W = (g==0)?Wf:(g==1)?Wi:(g==2)?Wc:Wo;
    size_t dst = (size_t)nb*65536 + (size_t)ks*2048 + (size_t)nt*1024 + (size_t)lane*8;
    #pragma unroll
    for (int e = 0; e < 8; ++e) {
        float v = W[(size_t)(k0 + e) * HID + j];
        unsigned short hi = f2bf(v);
        Wgpk[dst + e]       = hi;
        Wgpk[dst + 512 + e] = f2bf(v - bf2f(hi));
    }
}

// ---------------------------------------------------------------------------
// prep: W_out -> consecutive-n fragment panels (32 panels of 32 cols).
// ---------------------------------------------------------------------------
__global__ __launch_bounds__(256)
void prep_wout(const float* __restrict__ Wout, unsigned short* __restrict__ Wopk)
{
    int idx  = blockIdx.x * 256 + threadIdx.x;   // 131072 threads
    int lane = idx & 63;
    int nt   = (idx >> 6) & 1;
    int ks   = (idx >> 7) & 31;
    int nb   = idx >> 12;
    int f    = nb * 32 + nt * 16 + (lane & 15);
    int k0   = ks * 32 + (lane >> 4) * 8;
    size_t dst = (size_t)nb*65536 + (size_t)ks*2048 + (size_t)nt*1024 + (size_t)lane*8;
    #pragma unroll
    for (int e = 0; e < 8; ++e) {
        float v = Wout[(size_t)(k0 + e) * OUTF + f];
        unsigned short hi = f2bf(v);
        Wopk[dst + e]       = hi;
        Wopk[dst + 512 + e] = f2bf(v - bf2f(hi));
    }
}

// ---------------------------------------------------------------------------
// prep: h0 -> Hpk slot 0 (fragment layout); zero barrier counters.
// ---------------------------------------------------------------------------
__global__ __launch_bounds__(256)
void prep_h0(const float* __restrict__ h0,
             unsigned short* __restrict__ HpkH, unsigned short* __restrict__ HpkL,
             unsigned int* __restrict__ ctrs)
{
    int idx = blockIdx.x * 256 + threadIdx.x;   // 65536
    int b = idx >> 10, j = idx & 1023;
    float v = h0[idx];
    unsigned short hi = f2bf(v);
    size_t fo = hfrag_off(b, j);
    HpkH[fo] = hi;
    HpkL[fo] = f2bf(v - bf2f(hi));
    if (idx < 1024) ctrs[idx] = 0u;
}

// ---------------------------------------------------------------------------
// xproj (unchanged from round 4): Xp[tc][b][n] = x_t . Wg[:,n] + b_g[n].
// ---------------------------------------------------------------------------
__global__ __launch_bounds__(512, 4)
void xproj_mfma(const unsigned short* __restrict__ xh,
                const unsigned short* __restrict__ xl,
                const unsigned short* __restrict__ Wgpk,
                const float* __restrict__ bf_, const float* __restrict__ bi_,
                const float* __restrict__ bc_, const float* __restrict__ bo_,
                float* __restrict__ Xp, int t0)
{
    const int tid = threadIdx.x, lane = tid & 63, w = tid >> 6;
    const int mt = w & 3, nt = w >> 2;
    const int nb = blockIdx.x & 127, tc = blockIdx.x >> 7;
    const int t  = t0 + tc;
    const int n  = nb*32 + nt*16 + (lane & 15);
    const int g  = n >> 10, j = n & 1023;
    const float* bg = (g==0)?bf_:(g==1)?bi_:(g==2)?bc_:bo_;
    const float bias = bg[j];
    const int brow = mt*16 + (lane & 15);
    const size_t abase = ((size_t)brow*SEQ + t)*DIM + (lane >> 4)*8;
    const unsigned short* wb = Wgpk + (size_t)nb*65536 + (size_t)nt*1024 + (size_t)lane*8;

    f32x4 acc = {0.f, 0.f, 0.f, 0.f};
    #pragma unroll 4
    for (int ks = 0; ks < 32; ++ks) {
        bf16x8 axh = *(const bf16x8*)(xh + abase + ks*32);
        bf16x8 axl = *(const bf16x8*)(xl + abase + ks*32);
        bf16x8 wh  = *(const bf16x8*)(wb + (size_t)ks*2048);
        bf16x8 wl  = *(const bf16x8*)(wb + (size_t)ks*2048 + 512);
        acc = MFMA16(axh, wh, acc);
        acc = MFMA16(axl, wh, acc);
        acc = MFMA16(axh, wl, acc);
    }
    #pragma unroll
    for (int r = 0; r < 4; ++r)
        Xp[((size_t)tc*BATCH + mt*16 + (lane>>4)*4 + r)*NGATE + n] = acc[r] + bias;
}

// ---------------------------------------------------------------------------
// outproj: A now read from Hpk fragment layout -> coalesced 1KB bursts.
// ---------------------------------------------------------------------------
__global__ __launch_bounds__(512, 4)
void outproj_mfma(const unsigned short* __restrict__ HpkH,
                  const unsigned short* __restrict__ HpkL,
                  const unsigned short* __restrict__ Wopk,
                  const float* __restrict__ bout,
                  float* __restrict__ out, int t0)
{
    const int tid = threadIdx.x, lane = tid & 63, w = tid >> 6;
    const int mt = w & 3, nt = w >> 2;
    const int nb = blockIdx.x & 31, tc = blockIdx.x >> 5;
    const int t  = t0 + tc;
    const int n  = nb*32 + nt*16 + (lane & 15);
    const float bias = bout[n];
    const size_t abase = (size_t)(tc+1)*65536 + (size_t)mt*32*512 + (size_t)lane*8;
    const unsigned short* wb = Wopk + (size_t)nb*65536 + (size_t)nt*1024 + (size_t)lane*8;

    f32x4 acc = {0.f, 0.f, 0.f, 0.f};
    #pragma unroll 4
    for (int ks = 0; ks < 32; ++ks) {
        bf16x8 axh = *(const bf16x8*)(HpkH + abase + ks*512);
        bf16x8 axl = *(const bf16x8*)(HpkL + abase + ks*512);
        bf16x8 wh  = *(const bf16x8*)(wb + (size_t)ks*2048);
        bf16x8 wl  = *(const bf16x8*)(wb + (size_t)ks*2048 + 512);
        acc = MFMA16(axh, wh, acc);
        acc = MFMA16(axl, wh, acc);
        acc = MFMA16(axh, wl, acc);
    }
    #pragma unroll
    for (int r = 0; r < 4; ++r)
        out[((size_t)(mt*16 + (lane>>4)*4 + r)*SEQ + t)*OUTF + n] = acc[r] + bias;
}

// ---------------------------------------------------------------------------
// Recurrence v5. 256 blocks x 512 thr (1 block/CU, full chip).
// Block (mslice = bid&1, cslab = bid>>1): rows mslice*32..+32 x 32 gate cols
// (h-cols cslab*8..+8), FULL K. 8 waves = (mt 2) x (nt 2) x (kk 2); the two
// kk halves accumulate into separate Gbuf planes, summed in the cell phase.
// W panel permanent in LDS (128 KB, zero global W traffic per step).
// A-fragments load from Hpk ring: coalesced 1KB bursts (layout = fragment).
// Tree barrier: 16 group counters + 1 release counter, agent scope, no cache
// maintenance (ring slots are virgin addresses; stores are write-through).
// ---------------------------------------------------------------------------
__global__ __launch_bounds__(512, 2)
void lstm_mfma(const unsigned short* __restrict__ Wpk,
               const float* __restrict__ Xp,
               const float* __restrict__ c0,
               unsigned short* HpkH, unsigned short* HpkL,
               float* __restrict__ Cbuf,
               unsigned int* ctrs,          // [16*32] group ctrs, [544] release
               int t0, int nsteps)
{
    __shared__ __align__(16) unsigned short Wlds[65536];   // 128 KB
    __shared__ float Gbuf[2][32][33];                      // 8.4 KB
    const int tid  = threadIdx.x;
    const int bid  = blockIdx.x;
    const int lane = tid & 63;
    const int w    = tid >> 6;
    const int mt   = w & 1;
    const int ntw  = (w >> 1) & 1;
    const int kk   = w >> 2;
    const int mslice = bid & 1;
    const int cslab  = bid >> 1;

    // W panel -> LDS (once per dispatch)
    {
        const uint4* src = (const uint4*)(Wpk + (size_t)cslab * 65536);
        uint4* dst = (uint4*)Wlds;
        #pragma unroll
        for (int i = 0; i < 16; ++i) dst[tid + i*512] = src[tid + i*512];
    }

    // cell mapping: threads 0..255 each own one (b, j) cell
    const bool is_cell = tid < 256;
    const int bl = tid >> 3, jj = tid & 7;          // valid when is_cell
    const int b  = mslice*32 + bl;
    const int j  = cslab*8 + jj;
    float creg = 0.f;
    if (is_cell) creg = (t0 == 0) ? c0[(size_t)b*HID + j] : Cbuf[(size_t)b*HID + j];

    // store-side fragment constants
    const int bgrp_s   = mslice*2 + (bl >> 4);
    const int ks_s     = cslab >> 2;
    const int lane_s   = (bl & 15) | ((cslab & 3) << 4);
    const size_t fo_s  = ((size_t)(bgrp_s*32 + ks_s)*64 + lane_s)*8 + jj;

    // A-fragment constants
    const int bgrp = mslice*2 + mt;
    const int ks0  = kk * 16;
    const size_t abase0 = (size_t)(bgrp*32)*512 + (size_t)lane*8;

    __syncthreads();

    for (int tc = 0; tc < nsteps; ++tc) {
        const int st = t0 + tc;
        const unsigned short* ah = HpkH + (size_t)tc*65536 + abase0;
        const unsigned short* al = HpkL + (size_t)tc*65536 + abase0;

        // Xp prefetch (independent of h)
        float xf=0.f, xi=0.f, xc=0.f, xo=0.f;
        if (is_cell) {
            const float* xpb = Xp + ((size_t)tc*BATCH + b)*NGATE + cslab*8 + jj;
            xf = xpb[0]; xi = xpb[HID]; xc = xpb[2*HID]; xo = xpb[3*HID];
        }

        f32x4 acc = {0.f, 0.f, 0.f, 0.f};
        #pragma unroll
        for (int q = 0; q < 2; ++q) {
            bf16x8 af[16], wf[16];
            #pragma unroll
            for (int i = 0; i < 8; ++i) {
                const int ks = ks0 + q*8 + i;
                af[2*i]   = *(const bf16x8*)(ah + (size_t)ks*512);
                af[2*i+1] = *(const bf16x8*)(al + (size_t)ks*512);
                wf[2*i]   = *(const bf16x8*)(Wlds + ks*2048 + ntw*1024 + lane*8);
                wf[2*i+1] = *(const bf16x8*)(Wlds + ks*2048 + ntw*1024 + 512 + lane*8);
            }
            #pragma unroll
            for (int i = 0; i < 8; ++i) {
                acc = MFMA16(af[2*i],   wf[2*i],   acc);
                acc = MFMA16(af[2*i+1], wf[2*i],   acc);
                acc = MFMA16(af[2*i],   wf[2*i+1], acc);
            }
        }
        #pragma unroll
        for (int r = 0; r < 4; ++r)
            Gbuf[kk][mt*16 + (lane>>4)*4 + r][ntw*16 + (lane&15)] = acc[r];
        __syncthreads();

        if (is_cell) {
            float g0 = Gbuf[0][bl][     jj] + Gbuf[1][bl][     jj] + xf;
            float g1 = Gbuf[0][bl][ 8 + jj] + Gbuf[1][bl][ 8 + jj] + xi;
            float g2 = Gbuf[0][bl][16 + jj] + Gbuf[1][bl][16 + jj] + xc;
            float g3 = Gbuf[0][bl][24 + jj] + Gbuf[1][bl][24 + jj] + xo;
            float f_ = 1.f/(1.f + __expf(-g0));
            float i_ = 1.f/(1.f + __expf(-g1));
            float c_ = tanhf(g2);
            float o_ = 1.f/(1.f + __expf(-g3));
            float cn = f_*creg + i_*c_;
            float hn = o_*tanhf(cn);
            creg = cn;
            unsigned short hi16 = f2bf(hn);
            unsigned short lo16 = f2bf(hn - bf2f(hi16));
            size_t so = (size_t)(tc+1)*65536 + fo_s;
            __hip_atomic_store(HpkH + so, hi16, __ATOMIC_RELAXED, __HIP_MEMORY_SCOPE_AGENT);
            __hip_atomic_store(HpkL + so, lo16, __ATOMIC_RELAXED, __HIP_MEMORY_SCOPE_AGENT);
            if (tc == nsteps - 1) {   // refresh slot 0 for the next chunk
                __hip_atomic_store(HpkH + fo_s, hi16, __ATOMIC_RELAXED, __HIP_MEMORY_SCOPE_AGENT);
                __hip_atomic_store(HpkL + fo_s, lo16, __ATOMIC_RELAXED, __HIP_MEMORY_SCOPE_AGENT);
            }
        }

        // ---- tree barrier (no cache maintenance) ----
        asm volatile("s_waitcnt vmcnt(0)" ::: "memory");
        __syncthreads();
        if (tid == 0) {
            const unsigned grp = (unsigned)bid >> 4;
            unsigned old = __hip_atomic_fetch_add(&ctrs[grp*32], 1u,
                                                  __ATOMIC_RELAXED, __HIP_MEMORY_SCOPE_AGENT);
            if (old == 16u*(unsigned)st + 15u)
                __hip_atomic_fetch_add(&ctrs[544], 1u,
                                       __ATOMIC_RELAXED, __HIP_MEMORY_SCOPE_AGENT);
            const unsigned tgt = 16u * (unsigned)(st + 1);
            while (__hip_atomic_load(&ctrs[544], __ATOMIC_RELAXED,
                                     __HIP_MEMORY_SCOPE_AGENT) < tgt) { }
        }
        __syncthreads();
        asm volatile("" ::: "memory");
    }
    if (is_cell) Cbuf[(size_t)b*HID + j] = creg;
}

// ---------------------------------------------------------------------------

extern "C" void kernel_launch(void* const* d_in, const int* in_sizes, int n_in,
                              void* d_out, int out_size, void* d_ws, size_t ws_size,
                              hipStream_t stream)
{
    (void)in_sizes; (void)n_in; (void)out_size;
    const float* x    = (const float*)d_in[0];
    const float* h0   = (const float*)d_in[1];
    const float* c0   = (const float*)d_in[2];
    const float* Wf   = (const float*)d_in[3];
    const float* bf   = (const float*)d_in[4];
    const float* Wi   = (const float*)d_in[5];
    const float* bi   = (const float*)d_in[6];
    const float* Wc   = (const float*)d_in[7];
    const float* bc   = (const float*)d_in[8];
    const float* Wo   = (const float*)d_in[9];
    const float* bo   = (const float*)d_in[10];
    const float* Wout = (const float*)d_in[11];
    const float* bout = (const float*)d_in[12];
    float* out = (float*)d_out;

    const size_t SZ_WPK  = (size_t)16*1024*1024;
    const size_t SZ_WGPK = (size_t)16*1024*1024;
    const size_t SZ_WOPK = (size_t)4*1024*1024;
    const size_t SZ_XBF  = (size_t)BATCH*SEQ*DIM*2;   // 64 MB each
    const size_t SZ_CB   = (size_t)BATCH*HID*4;
    const size_t SZ_CTR  = 4096;
    const size_t fixed   = SZ_WPK + SZ_WGPK + SZ_WOPK + 2*SZ_XBF + SZ_CB + SZ_CTR;

    const int cand[6] = {256, 128, 64, 32, 16, 8};
    int chunk = 8;
    for (int i = 0; i < 6; ++i) {
        size_t need = fixed + (size_t)(cand[i]+1)*BATCH*HID*2*2
                            + (size_t)cand[i]*BATCH*NGATE*4;
        if (need <= ws_size) { chunk = cand[i]; break; }
    }

    char* p = (char*)d_ws;
    unsigned short* Wpk  = (unsigned short*)p; p += SZ_WPK;
    unsigned short* Wgpk = (unsigned short*)p; p += SZ_WGPK;
    unsigned short* Wopk = (unsigned short*)p; p += SZ_WOPK;
    unsigned short* xh   = (unsigned short*)p; p += SZ_XBF;
    unsigned short* xl   = (unsigned short*)p; p += SZ_XBF;
    float*          Cbuf = (float*)p;          p += SZ_CB;
    unsigned int*   ctrs = (unsigned int*)p;   p += SZ_CTR;
    unsigned short* HpkH = (unsigned short*)p; p += (size_t)(chunk+1)*BATCH*HID*2;
    unsigned short* HpkL = (unsigned short*)p; p += (size_t)(chunk+1)*BATCH*HID*2;
    float*          Xp   = (float*)p;

    prep_cvt_x<<<dim3(32768), dim3(256), 0, stream>>>(x, xh, xl);
    prep_w    <<<dim3(2048),  dim3(256), 0, stream>>>(Wf, Wi, Wc, Wo, Wpk);
    prep_wg   <<<dim3(2048),  dim3(256), 0, stream>>>(Wf, Wi, Wc, Wo, Wgpk);
    prep_wout <<<dim3(512),   dim3(256), 0, stream>>>(Wout, Wopk);
    prep_h0   <<<dim3(256),   dim3(256), 0, stream>>>(h0, HpkH, HpkL, ctrs);

    for (int t0 = 0; t0 < SEQ; t0 += chunk) {
        xproj_mfma<<<dim3(chunk*128), dim3(512), 0, stream>>>(
            xh, xl, Wgpk, bf, bi, bc, bo, Xp, t0);

        int t0i = t0, ns = chunk;
        void* args[9] = { (void*)&Wpk, (void*)&Xp, (void*)&c0,
                          (void*)&HpkH, (void*)&HpkL, (void*)&Cbuf, (void*)&ctrs,
                          (void*)&t0i, (void*)&ns };
        hipLaunchCooperativeKernel((const void*)lstm_mfma, dim3(NBLK), dim3(512),
                                   args, 0, stream);

        outproj_mfma<<<dim3(chunk*32), dim3(512), 0, stream>>>(
            HpkH, HpkL, Wopk, bout, out, t0);
    }
}